// Round 8
// baseline (247.102 us; speedup 1.0000x reference)
//
#include <hip/hip_runtime.h>

typedef unsigned short u16;
typedef unsigned int   u32;
typedef unsigned long long u64;
typedef __bf16 bf16x8 __attribute__((ext_vector_type(8)));
typedef float  f32x4  __attribute__((ext_vector_type(4)));
typedef u32    u32x4  __attribute__((ext_vector_type(4)));
typedef u16    u16x4  __attribute__((ext_vector_type(4)));
typedef u16    u16x8v __attribute__((ext_vector_type(8)));

#define R_DIM 400
#define F_DIM 256
#define M_TOT 51200

__device__ __forceinline__ u16 f2bf(float f) {
    union { float f; u32 i; } x; x.f = f;
    u32 r = x.i + 0x7FFFu + ((x.i >> 16) & 1u);   // RNE
    return (u16)(r >> 16);
}

// ---------------------------------------------------------------------------
// Kernel 1: convert fp32 W -> bf16 B-fragments (unchanged, verified).
// ---------------------------------------------------------------------------
__global__ __launch_bounds__(256) void wprep_f32(const float* __restrict__ W,
                                                 u16* __restrict__ Wf) {
    int g  = blockIdx.x * 256 + threadIdx.x;   // 0..8191
    int ks = g >> 10;
    int T  = (g >> 6) & 15;
    int L  = g & 63;
    int n  = T * 16 + (L & 15);
    int k  = ks * 32 + (L >> 4) * 8;
    const float* wp = W + (size_t)n * F_DIM + k;
    float4 lo = *(const float4*)wp;
    float4 hi = *(const float4*)(wp + 4);
    u16x8v t;
    t[0] = f2bf(lo.x); t[1] = f2bf(lo.y); t[2] = f2bf(lo.z); t[3] = f2bf(lo.w);
    t[4] = f2bf(hi.x); t[5] = f2bf(hi.y); t[6] = f2bf(hi.z); t[7] = f2bf(hi.w);
    *(u16x8v*)(Wf + (size_t)g * 8) = t;
}

// ---------------------------------------------------------------------------
// Ballot-based ranks (verified): rank(c) = #{j: A[j]>A[c]} + #{j<c: A[j]==A[c]}.
// ---------------------------------------------------------------------------
__device__ __forceinline__ void compute_slots(float4 v0, float4 v1r, int lane,
                                              int diag, u32 es[7], u32* dup_out) {
    float4 v1 = v1r;
    if (lane >= 36) { v1.x = -1.f; v1.y = -1.f; v1.z = -1.f; v1.w = -1.f; } // A in [0,1)
    float refs[6];
    refs[0] = __shfl(v0.x, 0);   // col 0
    refs[1] = __shfl(v0.x, 2);   // col 8
    refs[2] = __shfl(v0.y, 2);   // col 9
    refs[3] = __shfl(v0.z, 2);   // col 10
    refs[4] = __shfl(v0.w, 2);   // col 11
    refs[5] = __shfl(v0.x, 3);   // col 12
    const int cols[6] = {0, 8, 9, 10, 11, 12};
    float e0[4] = {v0.x, v0.y, v0.z, v0.w};
    float e1[4] = {v1.x, v1.y, v1.z, v1.w};
    u32 cnt[6];
#pragma unroll
    for (int k = 0; k < 6; k++) {
        int c = 0;
#pragma unroll
        for (int jj = 0; jj < 4; jj++) {
            int j = (lane << 2) + jj;
            c += __popcll(__ballot(e0[jj] > refs[k] ||
                                   (e0[jj] == refs[k] && j < cols[k])));
            c += __popcll(__ballot(e1[jj] > refs[k]));   // j>=256 > cols[k] always
        }
        cnt[k] = (u32)c;
    }
    bool dup = (diag == (int)cnt[0]) | (diag == (int)cnt[1]) | (diag == (int)cnt[2]) |
               (diag == (int)cnt[3]) | (diag == (int)cnt[4]) | (diag == (int)cnt[5]);
#pragma unroll
    for (int s = 0; s < 6; s++) es[s] = cnt[s];
    es[6] = (u32)diag;
    *dup_out = dup ? 1u : 0u;
}

// ---------------------------------------------------------------------------
// Kernel 2: GATHER — reverted verbatim to R6 (best measured: 59.7us).
// 1 row per wave, no LDS, no barriers; 12800 blocks x 256 threads.
// ~Fabric-bound at ~7.3 TB/s combined HBM+L3 service (R6/R7 invariance).
// ---------------------------------------------------------------------------
__global__ __launch_bounds__(256, 4) void gcn_gather(const float* __restrict__ A,
                                                     const float* __restrict__ feats,
                                                     u16* __restrict__ agg) {
    const int tid = threadIdx.x, wid = tid >> 6, lane = tid & 63;
    const int bid = (int)blockIdx.x;
    const int row = ((bid & 7) * 1600 + (bid >> 3)) * 4 + wid;
    const int bh  = row / R_DIM;
    const int dia = row - bh * R_DIM;

    const float* Ar = A + (size_t)row * R_DIM;
    float4 v0 = *(const float4*)(Ar + lane * 4);
    float4 v1 = *(const float4*)(Ar + (lane < 36 ? 256 + lane * 4 : 0));

    u32 es[7], dupm;
    compute_slots(v0, v1, lane, dia, es, &dupm);

    const float* fb = feats + (size_t)bh * R_DIM * F_DIM + lane * 4;
    float w[7]; float4 f[7];
#pragma unroll
    for (int s = 0; s < 7; s++) {
        u32 e = es[s];
        w[s] = Ar[e];                                    // L1-hot (row just read)
        f[s] = *(const float4*)(fb + (size_t)e * F_DIM); // coalesced 1KB
    }
    float a0 = 0.f, a1 = 0.f, a2 = 0.f, a3 = 0.f;
#pragma unroll
    for (int s = 0; s < 7; s++) {
        float ws = (s == 6 && dupm) ? 0.f : w[s];
        a0 += ws * f[s].x; a1 += ws * f[s].y; a2 += ws * f[s].z; a3 += ws * f[s].w;
    }
    u16x4 st = { f2bf(a0), f2bf(a1), f2bf(a2), f2bf(a3) };
    *(u16x4*)(agg + (size_t)row * F_DIM + lane * 4) = st;
}

// ---------------------------------------------------------------------------
// Kernel 3: GEMM v2 — 64 rows/block, 800 blocks, wave = one 16-row m-tile x
// ALL 16 n-tiles (acc[16]; K-loop+epilogue shape verified in R3, agg-fragment
// source verified in R6). Per ks: 1 agg load + 16 Wf loads + 16 MFMA
// -> Wf L1 traffic halved (209->104 MB), load:MFMA ~1:1.
// ---------------------------------------------------------------------------
__global__ __launch_bounds__(256) void gcn_gemm(const u16*  __restrict__ agg,
                                                const u16*  __restrict__ Wf,
                                                const float* __restrict__ bias,
                                                const float* __restrict__ feats,
                                                float* __restrict__ out) {
    __shared__ __align__(16) u16 probeA[16][32];
    __shared__ __align__(16) u16 probeB[16][32];

    const int tid = threadIdx.x, wid = tid >> 6, lane = tid & 63;
    const int bid = (int)blockIdx.x;
    const int m0  = ((bid & 7) * 100 + (bid >> 3)) * 64;   // 800 blocks, XCD swizzle
    const int kg  = (lane >> 4) << 3;

    // probe tiles: A[m][0]=m, A[m][1]=1; B[n][0]=16, B[n][1]=n  -> D=16m+n
    for (int e = tid; e < 512; e += 256) {
        int r = e >> 5, k = e & 31;
        probeA[r][k] = (k == 0) ? f2bf((float)r) : ((k == 1) ? f2bf(1.0f) : (u16)0);
        probeB[r][k] = (k == 0) ? f2bf(16.0f)    : ((k == 1) ? f2bf((float)r) : (u16)0);
    }
    __syncthreads();

    // ---- probe MFMA: decode true per-register (row,col) ----
    int rowi[4], coli[4];
    {
        bf16x8 pa = *(const bf16x8*)&probeA[lane & 15][kg];
        bf16x8 pb = *(const bf16x8*)&probeB[lane & 15][kg];
        f32x4 pd = {0.f, 0.f, 0.f, 0.f};
        pd = __builtin_amdgcn_mfma_f32_16x16x32_bf16(pa, pb, pd, 0, 0, 0);
#pragma unroll
        for (int reg = 0; reg < 4; reg++) {
            int v = (int)(pd[reg] + 0.5f);
            rowi[reg] = v >> 4;
            coli[reg] = v & 15;
        }
    }

    // ---- MFMA K-loop: wave wid owns rows m0+wid*16 .. +15, all 16 n-tiles ----
    f32x4 acc[16];
#pragma unroll
    for (int nt = 0; nt < 16; nt++) acc[nt] = (f32x4){0.f, 0.f, 0.f, 0.f};

    const u16* ab = agg + (size_t)(m0 + wid * 16 + (lane & 15)) * F_DIM + kg;
#pragma unroll
    for (int ks = 0; ks < 8; ks++) {
        bf16x8 af = *(const bf16x8*)(ab + ks * 32);
#pragma unroll
        for (int nt = 0; nt < 16; nt++) {
            u32x4 v = *(const u32x4*)(Wf + ((size_t)(ks * 16 + nt) * 64 + lane) * 8);
            bf16x8 b = __builtin_bit_cast(bf16x8, v);
            acc[nt] = __builtin_amdgcn_mfma_f32_16x16x32_bf16(af, b, acc[nt], 0, 0, 0);
        }
    }

    // ---- epilogue: relu(acc + b) + feats -> out (fp32) ----
#pragma unroll
    for (int nt = 0; nt < 16; nt++) {
        int nb = nt * 16;
#pragma unroll
        for (int reg = 0; reg < 4; reg++) {
            int gn = nb + coli[reg];
            float bn = bias[gn];
            int gm = m0 + wid * 16 + rowi[reg];
            size_t off = (size_t)gm * F_DIM + gn;
            out[off] = fmaxf(acc[nt][reg] + bn, 0.f) + feats[off];
        }
    }
}

extern "C" void kernel_launch(void* const* d_in, const int* in_sizes, int n_in,
                              void* d_out, int out_size, void* d_ws, size_t ws_size,
                              hipStream_t stream) {
    const float* A     = (const float*)d_in[0];   // [16,8,400,400] fp32
    const float* feats = (const float*)d_in[1];   // [16,8,400,256] fp32
    const float* W     = (const float*)d_in[2];   // [256,256] fp32
    const float* bias  = (const float*)d_in[3];   // [256] fp32
    float* out = (float*)d_out;                   // [16,8,400,256] fp32

    u16* Wf  = (u16*)d_ws;                                  // 128 KB
    u16* agg = (u16*)((char*)d_ws + (size_t)128 * 1024);    // 26.2 MB bf16 agg

    wprep_f32 <<<32,    256, 0, stream>>>(W, Wf);
    gcn_gather<<<12800, 256, 0, stream>>>(A, feats, agg);
    gcn_gemm  <<<800,   256, 0, stream>>>(agg, Wf, bias, feats, out);
}

// Round 9
// 224.501 us; speedup vs baseline: 1.1007x; 1.1007x over previous
//
#include <hip/hip_runtime.h>

typedef unsigned short u16;
typedef unsigned int   u32;
typedef unsigned long long u64;
typedef __bf16 bf16x8 __attribute__((ext_vector_type(8)));
typedef float  f32x4  __attribute__((ext_vector_type(4)));
typedef u32    u32x4  __attribute__((ext_vector_type(4)));
typedef u16    u16x4  __attribute__((ext_vector_type(4)));
typedef u16    u16x8v __attribute__((ext_vector_type(8)));

#define R_DIM 400
#define F_DIM 256
#define M_TOT 51200

__device__ __forceinline__ u16 f2bf(float f) {
    union { float f; u32 i; } x; x.f = f;
    u32 r = x.i + 0x7FFFu + ((x.i >> 16) & 1u);   // RNE
    return (u16)(r >> 16);
}

// ---------------------------------------------------------------------------
// Kernel 1: convert fp32 W -> bf16 B-fragments (unchanged, verified).
// ---------------------------------------------------------------------------
__global__ __launch_bounds__(256) void wprep_f32(const float* __restrict__ W,
                                                 u16* __restrict__ Wf) {
    int g  = blockIdx.x * 256 + threadIdx.x;   // 0..8191
    int ks = g >> 10;
    int T  = (g >> 6) & 15;
    int L  = g & 63;
    int n  = T * 16 + (L & 15);
    int k  = ks * 32 + (L >> 4) * 8;
    const float* wp = W + (size_t)n * F_DIM + k;
    float4 lo = *(const float4*)wp;
    float4 hi = *(const float4*)(wp + 4);
    u16x8v t;
    t[0] = f2bf(lo.x); t[1] = f2bf(lo.y); t[2] = f2bf(lo.z); t[3] = f2bf(lo.w);
    t[4] = f2bf(hi.x); t[5] = f2bf(hi.y); t[6] = f2bf(hi.z); t[7] = f2bf(hi.w);
    *(u16x8v*)(Wf + (size_t)g * 8) = t;
}

// ---------------------------------------------------------------------------
// Ballot-based ranks (verified): rank(c) = #{j: A[j]>A[c]} + #{j<c: A[j]==A[c]}.
// ---------------------------------------------------------------------------
__device__ __forceinline__ void compute_slots(float4 v0, float4 v1r, int lane,
                                              int diag, u32 es[7], u32* dup_out) {
    float4 v1 = v1r;
    if (lane >= 36) { v1.x = -1.f; v1.y = -1.f; v1.z = -1.f; v1.w = -1.f; } // A in [0,1)
    float refs[6];
    refs[0] = __shfl(v0.x, 0);   // col 0
    refs[1] = __shfl(v0.x, 2);   // col 8
    refs[2] = __shfl(v0.y, 2);   // col 9
    refs[3] = __shfl(v0.z, 2);   // col 10
    refs[4] = __shfl(v0.w, 2);   // col 11
    refs[5] = __shfl(v0.x, 3);   // col 12
    const int cols[6] = {0, 8, 9, 10, 11, 12};
    float e0[4] = {v0.x, v0.y, v0.z, v0.w};
    float e1[4] = {v1.x, v1.y, v1.z, v1.w};
    u32 cnt[6];
#pragma unroll
    for (int k = 0; k < 6; k++) {
        int c = 0;
#pragma unroll
        for (int jj = 0; jj < 4; jj++) {
            int j = (lane << 2) + jj;
            c += __popcll(__ballot(e0[jj] > refs[k] ||
                                   (e0[jj] == refs[k] && j < cols[k])));
            c += __popcll(__ballot(e1[jj] > refs[k]));   // j>=256 > cols[k] always
        }
        cnt[k] = (u32)c;
    }
    bool dup = (diag == (int)cnt[0]) | (diag == (int)cnt[1]) | (diag == (int)cnt[2]) |
               (diag == (int)cnt[3]) | (diag == (int)cnt[4]) | (diag == (int)cnt[5]);
#pragma unroll
    for (int s = 0; s < 6; s++) es[s] = cnt[s];
    es[6] = (u32)diag;
    *dup_out = dup ? 1u : 0u;
}

// ---------------------------------------------------------------------------
// Kernel 2: GATHER — R6 verbatim (best measured: 59.7us; fabric-bound:
// combined HBM+L3 service ~7.8 TB/s, invariant across 4 structural variants).
// ---------------------------------------------------------------------------
__global__ __launch_bounds__(256, 4) void gcn_gather(const float* __restrict__ A,
                                                     const float* __restrict__ feats,
                                                     u16* __restrict__ agg) {
    const int tid = threadIdx.x, wid = tid >> 6, lane = tid & 63;
    const int bid = (int)blockIdx.x;
    const int row = ((bid & 7) * 1600 + (bid >> 3)) * 4 + wid;
    const int bh  = row / R_DIM;
    const int dia = row - bh * R_DIM;

    const float* Ar = A + (size_t)row * R_DIM;
    float4 v0 = *(const float4*)(Ar + lane * 4);
    float4 v1 = *(const float4*)(Ar + (lane < 36 ? 256 + lane * 4 : 0));

    u32 es[7], dupm;
    compute_slots(v0, v1, lane, dia, es, &dupm);

    const float* fb = feats + (size_t)bh * R_DIM * F_DIM + lane * 4;
    float w[7]; float4 f[7];
#pragma unroll
    for (int s = 0; s < 7; s++) {
        u32 e = es[s];
        w[s] = Ar[e];                                    // L1-hot (row just read)
        f[s] = *(const float4*)(fb + (size_t)e * F_DIM); // coalesced 1KB
    }
    float a0 = 0.f, a1 = 0.f, a2 = 0.f, a3 = 0.f;
#pragma unroll
    for (int s = 0; s < 7; s++) {
        float ws = (s == 6 && dupm) ? 0.f : w[s];
        a0 += ws * f[s].x; a1 += ws * f[s].y; a2 += ws * f[s].z; a3 += ws * f[s].w;
    }
    u16x4 st = { f2bf(a0), f2bf(a1), f2bf(a2), f2bf(a3) };
    *(u16x4*)(agg + (size_t)row * F_DIM + lane * 4) = st;
}

// ---------------------------------------------------------------------------
// Kernel 3: GEMM — R6 shape verbatim (measured-by-subtraction ~31us in R6/R7;
// R8's re-tile regressed 2x and is abandoned). One shape-preserving change:
// NON-TEMPORAL epilogue traffic (feats re-read + out write are 52MB pure
// streams) so they don't evict L2-resident agg (3.3MB/XCD) and Wf (128KB).
// Data bits unchanged -> output bit-identical.
// ---------------------------------------------------------------------------
__global__ __launch_bounds__(256, 4) void gcn_gemm(const u16*  __restrict__ agg,
                                                   const u16*  __restrict__ Wf,
                                                   const float* __restrict__ bias,
                                                   const float* __restrict__ feats,
                                                   float* __restrict__ out) {
    __shared__ __align__(16) u16 probeA[16][32];
    __shared__ __align__(16) u16 probeB[16][32];

    const int tid = threadIdx.x, wid = tid >> 6, lane = tid & 63;
    const int bid = (int)blockIdx.x;
    const int m0  = ((bid & 7) * 200 + (bid >> 3)) * 32;
    const int kg  = (lane >> 4) << 3;
    const int mt  = wid & 1;         // m-tile within block
    const int nh  = wid >> 1;        // n-half: n-tiles nh*8 .. nh*8+7

    // probe tiles: A[m][0]=m, A[m][1]=1; B[n][0]=16, B[n][1]=n  -> D=16m+n
    for (int e = tid; e < 512; e += 256) {
        int r = e >> 5, k = e & 31;
        probeA[r][k] = (k == 0) ? f2bf((float)r) : ((k == 1) ? f2bf(1.0f) : (u16)0);
        probeB[r][k] = (k == 0) ? f2bf(16.0f)    : ((k == 1) ? f2bf((float)r) : (u16)0);
    }
    __syncthreads();

    // ---- probe MFMA: decode true per-register (row,col) ----
    int rowi[4], coli[4];
    {
        bf16x8 pa = *(const bf16x8*)&probeA[lane & 15][kg];
        bf16x8 pb = *(const bf16x8*)&probeB[lane & 15][kg];
        f32x4 pd = {0.f, 0.f, 0.f, 0.f};
        pd = __builtin_amdgcn_mfma_f32_16x16x32_bf16(pa, pb, pd, 0, 0, 0);
#pragma unroll
        for (int reg = 0; reg < 4; reg++) {
            int v = (int)(pd[reg] + 0.5f);
            rowi[reg] = v >> 4;
            coli[reg] = v & 15;
        }
    }

    // ---- MFMA K-loop: af per-lane direct from global agg ----
    f32x4 acc[8];
#pragma unroll
    for (int nt = 0; nt < 8; nt++) acc[nt] = (f32x4){0.f, 0.f, 0.f, 0.f};

    const u16* ab = agg + (size_t)(m0 + mt * 16 + (lane & 15)) * F_DIM + kg;
#pragma unroll
    for (int ks = 0; ks < 8; ks++) {
        bf16x8 af = *(const bf16x8*)(ab + ks * 32);
#pragma unroll
        for (int nt = 0; nt < 8; nt++) {
            int T = nh * 8 + nt;
            u32x4 v = *(const u32x4*)(Wf + ((size_t)(ks * 16 + T) * 64 + lane) * 8);
            bf16x8 b = __builtin_bit_cast(bf16x8, v);
            acc[nt] = __builtin_amdgcn_mfma_f32_16x16x32_bf16(af, b, acc[nt], 0, 0, 0);
        }
    }

    // ---- epilogue: relu(acc + b) + feats -> out (fp32), non-temporal ----
#pragma unroll
    for (int nt = 0; nt < 8; nt++) {
        int nb = (nh * 8 + nt) * 16;
#pragma unroll
        for (int reg = 0; reg < 4; reg++) {
            int gn = nb + coli[reg];
            float bn = bias[gn];
            int gm = m0 + mt * 16 + rowi[reg];
            size_t off = (size_t)gm * F_DIM + gn;
            float fv = __builtin_nontemporal_load(&feats[off]);
            __builtin_nontemporal_store(fmaxf(acc[nt][reg] + bn, 0.f) + fv, &out[off]);
        }
    }
}

extern "C" void kernel_launch(void* const* d_in, const int* in_sizes, int n_in,
                              void* d_out, int out_size, void* d_ws, size_t ws_size,
                              hipStream_t stream) {
    const float* A     = (const float*)d_in[0];   // [16,8,400,400] fp32
    const float* feats = (const float*)d_in[1];   // [16,8,400,256] fp32
    const float* W     = (const float*)d_in[2];   // [256,256] fp32
    const float* bias  = (const float*)d_in[3];   // [256] fp32
    float* out = (float*)d_out;                   // [16,8,400,256] fp32

    u16* Wf  = (u16*)d_ws;                                  // 128 KB
    u16* agg = (u16*)((char*)d_ws + (size_t)128 * 1024);    // 26.2 MB bf16 agg

    wprep_f32 <<<32,    256, 0, stream>>>(W, Wf);
    gcn_gather<<<12800, 256, 0, stream>>>(A, feats, agg);
    gcn_gemm  <<<1600,  256, 0, stream>>>(agg, Wf, bias, feats, out);
}

// Round 10
// 209.448 us; speedup vs baseline: 1.1798x; 1.0719x over previous
//
#include <hip/hip_runtime.h>

typedef unsigned short u16;
typedef unsigned int   u32;
typedef unsigned long long u64;
typedef __bf16 bf16x8 __attribute__((ext_vector_type(8)));
typedef float  f32x4  __attribute__((ext_vector_type(4)));
typedef u32    u32x4  __attribute__((ext_vector_type(4)));
typedef u16    u16x4  __attribute__((ext_vector_type(4)));
typedef u16    u16x8v __attribute__((ext_vector_type(8)));

#define R_DIM 400
#define F_DIM 256
#define M_TOT 51200

__device__ __forceinline__ u16 f2bf(float f) {
    union { float f; u32 i; } x; x.f = f;
    u32 r = x.i + 0x7FFFu + ((x.i >> 16) & 1u);   // RNE
    return (u16)(r >> 16);
}

// ---------------------------------------------------------------------------
// Ballot-based ranks (verified): rank(c) = #{j: A[j]>A[c]} + #{j<c: A[j]==A[c]}.
// ---------------------------------------------------------------------------
__device__ __forceinline__ void compute_slots(float4 v0, float4 v1r, int lane,
                                              int diag, u32 es[7], u32* dup_out) {
    float4 v1 = v1r;
    if (lane >= 36) { v1.x = -1.f; v1.y = -1.f; v1.z = -1.f; v1.w = -1.f; } // A in [0,1)
    float refs[6];
    refs[0] = __shfl(v0.x, 0);   // col 0
    refs[1] = __shfl(v0.x, 2);   // col 8
    refs[2] = __shfl(v0.y, 2);   // col 9
    refs[3] = __shfl(v0.z, 2);   // col 10
    refs[4] = __shfl(v0.w, 2);   // col 11
    refs[5] = __shfl(v0.x, 3);   // col 12
    const int cols[6] = {0, 8, 9, 10, 11, 12};
    float e0[4] = {v0.x, v0.y, v0.z, v0.w};
    float e1[4] = {v1.x, v1.y, v1.z, v1.w};
    u32 cnt[6];
#pragma unroll
    for (int k = 0; k < 6; k++) {
        int c = 0;
#pragma unroll
        for (int jj = 0; jj < 4; jj++) {
            int j = (lane << 2) + jj;
            c += __popcll(__ballot(e0[jj] > refs[k] ||
                                   (e0[jj] == refs[k] && j < cols[k])));
            c += __popcll(__ballot(e1[jj] > refs[k]));   // j>=256 > cols[k] always
        }
        cnt[k] = (u32)c;
    }
    bool dup = (diag == (int)cnt[0]) | (diag == (int)cnt[1]) | (diag == (int)cnt[2]) |
               (diag == (int)cnt[3]) | (diag == (int)cnt[4]) | (diag == (int)cnt[5]);
#pragma unroll
    for (int s = 0; s < 6; s++) es[s] = cnt[s];
    es[6] = (u32)diag;
    *dup_out = dup ? 1u : 0u;
}

// ---------------------------------------------------------------------------
// Kernel 1: GATHER + W-prep folded (one launch fewer).
// Blocks 0..31: W fp32 -> bf16 Wf fragments (verified wprep logic; consumed
//   only by gcn_gemm, which launches after this kernel completes).
// Blocks 32..12831: R6-verbatim gather, bid' = bid-32 (32%8==0 -> identical
//   XCD swizzle mapping). 1 row per wave, no LDS, no barriers.
// Gather is fabric-band-bound: ~7.8 TB/s combined HBM+L3 service, invariant
// across 4 structural variants (R2/R5/R6/R7).
// ---------------------------------------------------------------------------
__global__ __launch_bounds__(256, 4) void gcn_gather(const float* __restrict__ A,
                                                     const float* __restrict__ feats,
                                                     const float* __restrict__ W,
                                                     u16* __restrict__ Wf,
                                                     u16* __restrict__ agg) {
    const int tid = threadIdx.x, wid = tid >> 6, lane = tid & 63;
    const int bid = (int)blockIdx.x;

    if (bid < 32) {                    // ---- W-prep path (verified wprep_f32) ----
        int g  = bid * 256 + tid;      // 0..8191
        int ks = g >> 10;
        int T  = (g >> 6) & 15;
        int L  = g & 63;
        int n  = T * 16 + (L & 15);
        int k  = ks * 32 + (L >> 4) * 8;
        const float* wp = W + (size_t)n * F_DIM + k;
        float4 lo = *(const float4*)wp;
        float4 hi = *(const float4*)(wp + 4);
        u16x8v t;
        t[0] = f2bf(lo.x); t[1] = f2bf(lo.y); t[2] = f2bf(lo.z); t[3] = f2bf(lo.w);
        t[4] = f2bf(hi.x); t[5] = f2bf(hi.y); t[6] = f2bf(hi.z); t[7] = f2bf(hi.w);
        *(u16x8v*)(Wf + (size_t)g * 8) = t;
        return;
    }

    const int b   = bid - 32;
    const int row = ((b & 7) * 1600 + (b >> 3)) * 4 + wid;
    const int bh  = row / R_DIM;
    const int dia = row - bh * R_DIM;

    const float* Ar = A + (size_t)row * R_DIM;
    float4 v0 = *(const float4*)(Ar + lane * 4);
    float4 v1 = *(const float4*)(Ar + (lane < 36 ? 256 + lane * 4 : 0));

    u32 es[7], dupm;
    compute_slots(v0, v1, lane, dia, es, &dupm);

    const float* fb = feats + (size_t)bh * R_DIM * F_DIM + lane * 4;
    float w[7]; float4 f[7];
#pragma unroll
    for (int s = 0; s < 7; s++) {
        u32 e = es[s];
        w[s] = Ar[e];                                    // L1-hot (row just read)
        f[s] = *(const float4*)(fb + (size_t)e * F_DIM); // coalesced 1KB
    }
    float a0 = 0.f, a1 = 0.f, a2 = 0.f, a3 = 0.f;
#pragma unroll
    for (int s = 0; s < 7; s++) {
        float ws = (s == 6 && dupm) ? 0.f : w[s];
        a0 += ws * f[s].x; a1 += ws * f[s].y; a2 += ws * f[s].z; a3 += ws * f[s].w;
    }
    u16x4 st = { f2bf(a0), f2bf(a1), f2bf(a2), f2bf(a3) };
    *(u16x4*)(agg + (size_t)row * F_DIM + lane * 4) = st;
}

// ---------------------------------------------------------------------------
// Kernel 2: GEMM — R6 verbatim (best measured config; ~31us by subtraction).
// NT epilogue reverted: R9 showed NT loads demote L2/L3-hot feats lines (+10us).
// ---------------------------------------------------------------------------
__global__ __launch_bounds__(256, 4) void gcn_gemm(const u16*  __restrict__ agg,
                                                   const u16*  __restrict__ Wf,
                                                   const float* __restrict__ bias,
                                                   const float* __restrict__ feats,
                                                   float* __restrict__ out) {
    __shared__ __align__(16) u16 probeA[16][32];
    __shared__ __align__(16) u16 probeB[16][32];

    const int tid = threadIdx.x, wid = tid >> 6, lane = tid & 63;
    const int bid = (int)blockIdx.x;
    const int m0  = ((bid & 7) * 200 + (bid >> 3)) * 32;
    const int kg  = (lane >> 4) << 3;
    const int mt  = wid & 1;         // m-tile within block
    const int nh  = wid >> 1;        // n-half: n-tiles nh*8 .. nh*8+7

    // probe tiles: A[m][0]=m, A[m][1]=1; B[n][0]=16, B[n][1]=n  -> D=16m+n
    for (int e = tid; e < 512; e += 256) {
        int r = e >> 5, k = e & 31;
        probeA[r][k] = (k == 0) ? f2bf((float)r) : ((k == 1) ? f2bf(1.0f) : (u16)0);
        probeB[r][k] = (k == 0) ? f2bf(16.0f)    : ((k == 1) ? f2bf((float)r) : (u16)0);
    }
    __syncthreads();

    // ---- probe MFMA: decode true per-register (row,col) ----
    int rowi[4], coli[4];
    {
        bf16x8 pa = *(const bf16x8*)&probeA[lane & 15][kg];
        bf16x8 pb = *(const bf16x8*)&probeB[lane & 15][kg];
        f32x4 pd = {0.f, 0.f, 0.f, 0.f};
        pd = __builtin_amdgcn_mfma_f32_16x16x32_bf16(pa, pb, pd, 0, 0, 0);
#pragma unroll
        for (int reg = 0; reg < 4; reg++) {
            int v = (int)(pd[reg] + 0.5f);
            rowi[reg] = v >> 4;
            coli[reg] = v & 15;
        }
    }

    // ---- MFMA K-loop: af per-lane direct from global agg ----
    f32x4 acc[8];
#pragma unroll
    for (int nt = 0; nt < 8; nt++) acc[nt] = (f32x4){0.f, 0.f, 0.f, 0.f};

    const u16* ab = agg + (size_t)(m0 + mt * 16 + (lane & 15)) * F_DIM + kg;
#pragma unroll
    for (int ks = 0; ks < 8; ks++) {
        bf16x8 af = *(const bf16x8*)(ab + ks * 32);
#pragma unroll
        for (int nt = 0; nt < 8; nt++) {
            int T = nh * 8 + nt;
            u32x4 v = *(const u32x4*)(Wf + ((size_t)(ks * 16 + T) * 64 + lane) * 8);
            bf16x8 b = __builtin_bit_cast(bf16x8, v);
            acc[nt] = __builtin_amdgcn_mfma_f32_16x16x32_bf16(af, b, acc[nt], 0, 0, 0);
        }
    }

    // ---- epilogue: relu(acc + b) + feats -> out (fp32) ----
#pragma unroll
    for (int nt = 0; nt < 8; nt++) {
        int nb = (nh * 8 + nt) * 16;
#pragma unroll
        for (int reg = 0; reg < 4; reg++) {
            int gn = nb + coli[reg];
            float bn = bias[gn];
            int gm = m0 + mt * 16 + rowi[reg];
            size_t off = (size_t)gm * F_DIM + gn;
            out[off] = fmaxf(acc[nt][reg] + bn, 0.f) + feats[off];
        }
    }
}

extern "C" void kernel_launch(void* const* d_in, const int* in_sizes, int n_in,
                              void* d_out, int out_size, void* d_ws, size_t ws_size,
                              hipStream_t stream) {
    const float* A     = (const float*)d_in[0];   // [16,8,400,400] fp32
    const float* feats = (const float*)d_in[1];   // [16,8,400,256] fp32
    const float* W     = (const float*)d_in[2];   // [256,256] fp32
    const float* bias  = (const float*)d_in[3];   // [256] fp32
    float* out = (float*)d_out;                   // [16,8,400,256] fp32

    u16* Wf  = (u16*)d_ws;                                  // 128 KB
    u16* agg = (u16*)((char*)d_ws + (size_t)128 * 1024);    // 26.2 MB bf16 agg

    gcn_gather<<<12832, 256, 0, stream>>>(A, feats, W, Wf, agg);
    gcn_gemm  <<<1600,  256, 0, stream>>>(agg, Wf, bias, feats, out);
}